// Round 1
// baseline (1130.961 us; speedup 1.0000x reference)
//
#include <hip/hip_runtime.h>
#include <math.h>

#define CHUNK 2048

static inline size_t align_up(size_t x, size_t a){ return (x + a - 1) & ~(a - 1); }

// ---------------- graph prep ----------------

__global__ __launch_bounds__(256) void k_hist(const int* __restrict__ col, int* __restrict__ cnt, int E){
  int e = blockIdx.x * 256 + threadIdx.x;
  if (e < E) atomicAdd(&cnt[col[e]], 1);
}

__global__ __launch_bounds__(256) void k_dinv(const int* __restrict__ cnt, float* __restrict__ dinv, int n){
  int i = blockIdx.x * 256 + threadIdx.x;
  if (i < n){
    double d = (double)(cnt[i] + 1);          // +1 self-loop
    dinv[i] = (float)(1.0 / sqrt(d));
  }
}

__global__ __launch_bounds__(256) void k_scan1(const int* __restrict__ cnt, int* __restrict__ csum, int n){
  __shared__ int red[256];
  int b = blockIdx.x, t = threadIdx.x;
  int base = b * CHUNK + t * 8;
  int s = 0;
  #pragma unroll
  for (int j = 0; j < 8; ++j){ int idx = base + j; if (idx < n) s += cnt[idx]; }
  red[t] = s; __syncthreads();
  for (int off = 128; off > 0; off >>= 1){
    if (t < off) red[t] += red[t + off];
    __syncthreads();
  }
  if (t == 0) csum[b] = red[0];
}

__global__ void k_scan2(const int* __restrict__ csum, int* __restrict__ coff, int nch,
                        int* __restrict__ row_ptr, int n, int E){
  if (blockIdx.x == 0 && threadIdx.x == 0){
    int run = 0;
    for (int b = 0; b < nch; ++b){ coff[b] = run; run += csum[b]; }
    row_ptr[n] = E;
  }
}

__global__ __launch_bounds__(256) void k_scan3(const int* __restrict__ cnt, const int* __restrict__ coff,
                                               int* __restrict__ row_ptr, int n){
  __shared__ int sd[256];
  int b = blockIdx.x, t = threadIdx.x;
  int base = b * CHUNK + t * 8;
  int c[8]; int s = 0;
  #pragma unroll
  for (int j = 0; j < 8; ++j){ int idx = base + j; c[j] = (idx < n) ? cnt[idx] : 0; s += c[j]; }
  sd[t] = s; __syncthreads();
  for (int off = 1; off < 256; off <<= 1){
    int v = sd[t];
    if (t >= off) v += sd[t - off];
    __syncthreads(); sd[t] = v; __syncthreads();
  }
  int run = coff[b] + sd[t] - s;   // exclusive prefix for this thread
  #pragma unroll
  for (int j = 0; j < 8; ++j){ int idx = base + j; if (idx < n) row_ptr[idx] = run; run += c[j]; }
}

__global__ __launch_bounds__(256) void k_scatter(const int* __restrict__ ei, const float* __restrict__ dinv,
                                                 int* __restrict__ fill, int* __restrict__ ssrc,
                                                 float* __restrict__ snrm, int E){
  int e = blockIdx.x * 256 + threadIdx.x;
  if (e >= E) return;
  int s = ei[e], d = ei[E + e];
  int p = atomicAdd(&fill[d], 1);
  ssrc[p] = s;
  snrm[p] = dinv[s] * dinv[d];
}

__global__ __launch_bounds__(256) void k_gstart(const int* __restrict__ batch, int* __restrict__ gstart,
                                                int n, int G){
  int i = blockIdx.x * 256 + threadIdx.x;
  if (i >= n) return;
  int cb = batch[i];
  if (i == 0){ for (int g = 0; g <= cb; ++g) gstart[g] = 0; }
  else { int pb = batch[i - 1]; for (int g = pb + 1; g <= cb; ++g) gstart[g] = i; }
  if (i == n - 1){ for (int g = cb + 1; g <= G; ++g) gstart[g] = n; }
}

// ---------------- GEMM: C[N,128] = A[N,128] @ W[128,128] ----------------
// 128x128 tile per block, 256 threads, 8 rows x 8 cols per thread.
// W in LDS (2-way-aliased b128 reads via col split {4cg, 64+4cg}); A from global
// (16 lanes share each address -> A tile fetched once per block).

__global__ __launch_bounds__(256, 2) void k_gemm(const float* __restrict__ A, const float* __restrict__ W,
                                                 float* __restrict__ C, int n){
  __shared__ __align__(16) float Ws[128 * 128];
  int t = threadIdx.x;
  {
    const float4* Wv = (const float4*)W;
    float4* Sv = (float4*)Ws;
    #pragma unroll
    for (int i = 0; i < 16; ++i) Sv[t + 256 * i] = Wv[t + 256 * i];
  }
  __syncthreads();

  int rg = t >> 4, cg = t & 15;
  int r0 = blockIdx.x * 128 + rg * 8;
  int ca = cg * 4, cb = 64 + cg * 4;

  float4 acc_a[8], acc_b[8];
  #pragma unroll
  for (int j = 0; j < 8; ++j){ acc_a[j] = make_float4(0,0,0,0); acc_b[j] = make_float4(0,0,0,0); }

  size_t rowp[8];
  #pragma unroll
  for (int j = 0; j < 8; ++j){
    int rr = r0 + j; if (rr > n - 1) rr = n - 1;   // clamp tail (stores guarded)
    rowp[j] = (size_t)rr * 128;
  }

  #pragma unroll 2
  for (int k4 = 0; k4 < 128; k4 += 4){
    float4 a[8];
    #pragma unroll
    for (int j = 0; j < 8; ++j) a[j] = *(const float4*)(A + rowp[j] + k4);
    #pragma unroll
    for (int q = 0; q < 4; ++q){
      float4 wa = *(const float4*)(Ws + (k4 + q) * 128 + ca);
      float4 wb = *(const float4*)(Ws + (k4 + q) * 128 + cb);
      #pragma unroll
      for (int j = 0; j < 8; ++j){
        float av = (q == 0) ? a[j].x : (q == 1) ? a[j].y : (q == 2) ? a[j].z : a[j].w;
        acc_a[j].x += av * wa.x; acc_a[j].y += av * wa.y; acc_a[j].z += av * wa.z; acc_a[j].w += av * wa.w;
        acc_b[j].x += av * wb.x; acc_b[j].y += av * wb.y; acc_b[j].z += av * wb.z; acc_b[j].w += av * wb.w;
      }
    }
  }

  #pragma unroll
  for (int j = 0; j < 8; ++j){
    int rr = r0 + j;
    if (rr < n){
      *(float4*)(C + (size_t)rr * 128 + ca) = acc_a[j];
      *(float4*)(C + (size_t)rr * 128 + cb) = acc_b[j];
    }
  }
}

// ---------------- aggregate: h_out = tanh(A_norm * hw + b) ----------------
// one wave per node; lane handles 2 features (float2 gather)

__global__ __launch_bounds__(256) void k_agg(const float* __restrict__ hw, const int* __restrict__ rp,
                                             const int* __restrict__ ssrc, const float* __restrict__ snrm,
                                             const float* __restrict__ dinv, const float* __restrict__ bias,
                                             float* __restrict__ hout, int n){
  int gw = (blockIdx.x * 256 + threadIdx.x) >> 6;   // node = global wave id
  if (gw >= n) return;
  int lane = threadIdx.x & 63;
  int f = lane * 2;

  int e0 = rp[gw], e1 = rp[gw + 1];
  float ax = 0.f, ay = 0.f;
  int sn = 0; float nn = 0.f;
  if (e0 < e1){ sn = ssrc[e0]; nn = snrm[e0]; }
  for (int e = e0; e < e1; ++e){
    int s = sn; float nv = nn;
    int e2 = e + 1;
    if (e2 < e1){ sn = ssrc[e2]; nn = snrm[e2]; }     // prefetch next edge meta
    const float2 v = *(const float2*)(hw + (size_t)s * 128 + f);
    ax = fmaf(nv, v.x, ax); ay = fmaf(nv, v.y, ay);
  }
  float di = dinv[gw]; float d2 = di * di;
  const float2 vs = *(const float2*)(hw + (size_t)gw * 128 + f);
  ax = fmaf(d2, vs.x, ax); ay = fmaf(d2, vs.y, ay);
  ax = tanhf(ax + bias[f]); ay = tanhf(ay + bias[f + 1]);
  *(float2*)(hout + (size_t)gw * 128 + f) = make_float2(ax, ay);
}

// ---------------- pool (max+mean per graph) fused with linear head ----------------

__global__ __launch_bounds__(256) void k_pool(const float* __restrict__ h, const int* __restrict__ gstart,
                                              const float* __restrict__ Wl, const float* __restrict__ bl,
                                              float* __restrict__ out){
  int g = blockIdx.x;
  int t = threadIdx.x;
  int f = t & 127, half = t >> 7;
  int i0 = gstart[g], i1 = gstart[g + 1];

  float mx = -INFINITY, sm = 0.f;
  for (int i = i0 + half; i < i1; i += 2){
    float v = h[(size_t)i * 128 + f];
    mx = fmaxf(mx, v); sm += v;
  }
  __shared__ float smx[128], ssm[128], sred[2];
  if (half){ smx[f] = mx; ssm[f] = sm; }
  __syncthreads();
  float contrib = 0.f;
  if (!half){
    mx = fmaxf(mx, smx[f]); sm += ssm[f];
    int cnt = i1 - i0;
    if (cnt <= 0) mx = 0.f;
    float mn = sm / (float)(cnt > 0 ? cnt : 1);
    contrib = mx * Wl[f] + mn * Wl[128 + f];
  }
  for (int o = 32; o > 0; o >>= 1) contrib += __shfl_down(contrib, o);
  if (!half && (t & 63) == 0) sred[t >> 6] = contrib;
  __syncthreads();
  if (t == 0) out[g] = sred[0] + sred[1] + bl[0];
}

// ---------------- launch ----------------

extern "C" void kernel_launch(void* const* d_in, const int* in_sizes, int n_in,
                              void* d_out, int out_size, void* d_ws, size_t ws_size,
                              hipStream_t stream){
  const float* x     = (const float*)d_in[0];
  const int*   ei    = (const int*)d_in[1];
  const int*   batch = (const int*)d_in[2];
  const float* W[4]  = {(const float*)d_in[3], (const float*)d_in[5], (const float*)d_in[7], (const float*)d_in[9]};
  const float* B[4]  = {(const float*)d_in[4], (const float*)d_in[6], (const float*)d_in[8], (const float*)d_in[10]};
  const float* Wl    = (const float*)d_in[11];
  const float* bl    = (const float*)d_in[12];
  float* out = (float*)d_out;

  int N = in_sizes[0] / 128;
  int E = in_sizes[1] / 2;
  int G = out_size;

  char* ws = (char*)d_ws;
  size_t off = 0;
  auto alloc = [&](size_t bytes) -> void* {
    void* p = ws + off; off = align_up(off + bytes, 256); return p;
  };
  int*   deg   = (int*)  alloc((size_t)N * 4);
  float* dinv  = (float*)alloc((size_t)N * 4);
  int*   rp    = (int*)  alloc((size_t)(N + 1) * 4);
  int*   fill  = (int*)  alloc((size_t)N * 4);
  int nch = (N + CHUNK - 1) / CHUNK;
  int*   csum  = (int*)  alloc((size_t)nch * 4);
  int*   coff  = (int*)  alloc((size_t)nch * 4);
  int*   gst   = (int*)  alloc((size_t)(G + 1) * 4);
  int*   ssrc  = (int*)  alloc((size_t)E * 4);
  float* snrm  = (float*)alloc((size_t)E * 4);
  float* hw    = (float*)alloc((size_t)N * 128 * 4);
  float* h     = (float*)alloc((size_t)N * 128 * 4);

  hipMemsetAsync(deg, 0, (size_t)N * 4, stream);

  int gE = (E + 255) / 256, gN = (N + 255) / 256;
  k_hist <<<gE, 256, 0, stream>>>(ei + E, deg, E);
  k_dinv <<<gN, 256, 0, stream>>>(deg, dinv, N);
  k_scan1<<<nch, 256, 0, stream>>>(deg, csum, N);
  k_scan2<<<1, 64, 0, stream>>>(csum, coff, nch, rp, N, E);
  k_scan3<<<nch, 256, 0, stream>>>(deg, coff, rp, N);
  hipMemcpyAsync(fill, rp, (size_t)N * 4, hipMemcpyDeviceToDevice, stream);
  k_scatter<<<gE, 256, 0, stream>>>(ei, dinv, fill, ssrc, snrm, E);
  k_gstart <<<gN, 256, 0, stream>>>(batch, gst, N, G);

  int gemmG = (N + 127) / 128;
  int aggG  = (N + 3) / 4;
  const float* hin = x;
  for (int l = 0; l < 4; ++l){
    k_gemm<<<gemmG, 256, 0, stream>>>(hin, W[l], hw, N);
    k_agg <<<aggG, 256, 0, stream>>>(hw, rp, ssrc, snrm, dinv, B[l], h, N);
    hin = h;
  }
  k_pool<<<G, 256, 0, stream>>>(h, gst, Wl, bl, out);
}

// Round 2
// 1027.317 us; speedup vs baseline: 1.1009x; 1.1009x over previous
//
#include <hip/hip_runtime.h>
#include <math.h>

#define CHUNK 2048
#define PSPLIT 8

typedef float f2v __attribute__((ext_vector_type(2)));

static inline size_t align_up(size_t x, size_t a){ return (x + a - 1) & ~(a - 1); }

// ---------------- graph prep ----------------

__global__ __launch_bounds__(256) void k_hist(const int* __restrict__ col, int* __restrict__ cnt, int E){
  int e = blockIdx.x * 256 + threadIdx.x;
  if (e < E) atomicAdd(&cnt[col[e]], 1);
}

__global__ __launch_bounds__(256) void k_dinv(const int* __restrict__ cnt, float* __restrict__ dinv, int n){
  int i = blockIdx.x * 256 + threadIdx.x;
  if (i < n){
    double d = (double)(cnt[i] + 1);          // +1 self-loop
    dinv[i] = (float)(1.0 / sqrt(d));
  }
}

__global__ __launch_bounds__(256) void k_scan1(const int* __restrict__ cnt, int* __restrict__ csum, int n){
  __shared__ int red[256];
  int b = blockIdx.x, t = threadIdx.x;
  int base = b * CHUNK + t * 8;
  int s = 0;
  #pragma unroll
  for (int j = 0; j < 8; ++j){ int idx = base + j; if (idx < n) s += cnt[idx]; }
  red[t] = s; __syncthreads();
  for (int off = 128; off > 0; off >>= 1){
    if (t < off) red[t] += red[t + off];
    __syncthreads();
  }
  if (t == 0) csum[b] = red[0];
}

__global__ void k_scan2(const int* __restrict__ csum, int* __restrict__ coff, int nch,
                        int* __restrict__ row_ptr, int n, int E){
  if (blockIdx.x == 0 && threadIdx.x == 0){
    int run = 0;
    for (int b = 0; b < nch; ++b){ coff[b] = run; run += csum[b]; }
    row_ptr[n] = E;
  }
}

__global__ __launch_bounds__(256) void k_scan3(const int* __restrict__ cnt, const int* __restrict__ coff,
                                               int* __restrict__ row_ptr, int* __restrict__ fill, int n){
  __shared__ int sd[256];
  int b = blockIdx.x, t = threadIdx.x;
  int base = b * CHUNK + t * 8;
  int c[8]; int s = 0;
  #pragma unroll
  for (int j = 0; j < 8; ++j){ int idx = base + j; c[j] = (idx < n) ? cnt[idx] : 0; s += c[j]; }
  sd[t] = s; __syncthreads();
  for (int off = 1; off < 256; off <<= 1){
    int v = sd[t];
    if (t >= off) v += sd[t - off];
    __syncthreads(); sd[t] = v; __syncthreads();
  }
  int run = coff[b] + sd[t] - s;   // exclusive prefix for this thread
  #pragma unroll
  for (int j = 0; j < 8; ++j){
    int idx = base + j;
    if (idx < n){ row_ptr[idx] = run; fill[idx] = run; }
    run += c[j];
  }
}

__global__ __launch_bounds__(256) void k_scatter(const int* __restrict__ ei,
                                                 int* __restrict__ fill, int* __restrict__ ssrc, int E){
  int e = blockIdx.x * 256 + threadIdx.x;
  if (e >= E) return;
  int s = ei[e], d = ei[E + e];
  int p = atomicAdd(&fill[d], 1);
  ssrc[p] = s;
}

__global__ __launch_bounds__(256) void k_gstart(const int* __restrict__ batch, int* __restrict__ gstart,
                                                int n, int G){
  int i = blockIdx.x * 256 + threadIdx.x;
  if (i >= n) return;
  int cb = batch[i];
  if (i == 0){ for (int g = 0; g <= cb; ++g) gstart[g] = 0; }
  else { int pb = batch[i - 1]; for (int g = pb + 1; g <= cb; ++g) gstart[g] = i; }
  if (i == n - 1){ for (int g = cb + 1; g <= G; ++g) gstart[g] = n; }
}

// ---------------- GEMM: C[N,128] = (A[N,128] @ W[128,128]) * dinv[row] ----------------
// 128x128 tile per block, 256 threads, 8 rows x 8 cols per thread.
// W in LDS (2-way-aliased b128 reads via col split {4cg, 64+4cg}); A from global
// (16 lanes share each address -> A tile fetched once per block).

__global__ __launch_bounds__(256, 2) void k_gemm(const float* __restrict__ A, const float* __restrict__ W,
                                                 const float* __restrict__ dinv,
                                                 float* __restrict__ C, int n){
  __shared__ __align__(16) float Ws[128 * 128];
  int t = threadIdx.x;
  {
    const float4* Wv = (const float4*)W;
    float4* Sv = (float4*)Ws;
    #pragma unroll
    for (int i = 0; i < 16; ++i) Sv[t + 256 * i] = Wv[t + 256 * i];
  }
  __syncthreads();

  int rg = t >> 4, cg = t & 15;
  int r0 = blockIdx.x * 128 + rg * 8;
  int ca = cg * 4, cb = 64 + cg * 4;

  float4 acc_a[8], acc_b[8];
  #pragma unroll
  for (int j = 0; j < 8; ++j){ acc_a[j] = make_float4(0,0,0,0); acc_b[j] = make_float4(0,0,0,0); }

  size_t rowp[8];
  #pragma unroll
  for (int j = 0; j < 8; ++j){
    int rr = r0 + j; if (rr > n - 1) rr = n - 1;   // clamp tail (stores guarded)
    rowp[j] = (size_t)rr * 128;
  }

  #pragma unroll 2
  for (int k4 = 0; k4 < 128; k4 += 4){
    float4 a[8];
    #pragma unroll
    for (int j = 0; j < 8; ++j) a[j] = *(const float4*)(A + rowp[j] + k4);
    #pragma unroll
    for (int q = 0; q < 4; ++q){
      float4 wa = *(const float4*)(Ws + (k4 + q) * 128 + ca);
      float4 wb = *(const float4*)(Ws + (k4 + q) * 128 + cb);
      #pragma unroll
      for (int j = 0; j < 8; ++j){
        float av = (q == 0) ? a[j].x : (q == 1) ? a[j].y : (q == 2) ? a[j].z : a[j].w;
        acc_a[j].x += av * wa.x; acc_a[j].y += av * wa.y; acc_a[j].z += av * wa.z; acc_a[j].w += av * wa.w;
        acc_b[j].x += av * wb.x; acc_b[j].y += av * wb.y; acc_b[j].z += av * wb.z; acc_b[j].w += av * wb.w;
      }
    }
  }

  #pragma unroll
  for (int j = 0; j < 8; ++j){
    int rr = r0 + j;
    if (rr < n){
      float sc = dinv[rr];
      float4 va = acc_a[j], vb = acc_b[j];
      va.x *= sc; va.y *= sc; va.z *= sc; va.w *= sc;
      vb.x *= sc; vb.y *= sc; vb.z *= sc; vb.w *= sc;
      *(float4*)(C + (size_t)rr * 128 + ca) = va;
      *(float4*)(C + (size_t)rr * 128 + cb) = vb;
    }
  }
}

// ---------------- aggregate: h_out = tanh(dinv[d]*(sum hw'[src] + hw'[d]) + b) ----------------
// one wave per node; lane handles 2 features (float2 gather).
// Edge meta: ONE coalesced per-lane load + __shfl distribution; gathers 8-deep.

__global__ __launch_bounds__(256) void k_agg(const float* __restrict__ hwp, const int* __restrict__ rp,
                                             const int* __restrict__ ssrc,
                                             const float* __restrict__ dinv, const float* __restrict__ bias,
                                             float* __restrict__ hout, int n){
  int gw = (blockIdx.x * 256 + threadIdx.x) >> 6;   // node = global wave id
  if (gw >= n) return;
  int lane = threadIdx.x & 63;
  int f = lane * 2;
  const float* base = hwp + f;

  int e0 = rp[gw], e1 = rp[gw + 1];
  float ax = 0.f, ay = 0.f;
  for (int eb = e0; eb < e1; eb += 64){
    int m = e1 - eb; if (m > 64) m = 64;
    int sl = (lane < m) ? ssrc[eb + lane] : 0;      // one coalesced 4B load per lane
    int j = 0;
    for (; j + 8 <= m; j += 8){
      int s0 = __shfl(sl, j),     s1 = __shfl(sl, j + 1), s2 = __shfl(sl, j + 2), s3 = __shfl(sl, j + 3);
      int s4 = __shfl(sl, j + 4), s5 = __shfl(sl, j + 5), s6 = __shfl(sl, j + 6), s7 = __shfl(sl, j + 7);
      float2 v0 = *(const float2*)(base + (size_t)s0 * 128);
      float2 v1 = *(const float2*)(base + (size_t)s1 * 128);
      float2 v2 = *(const float2*)(base + (size_t)s2 * 128);
      float2 v3 = *(const float2*)(base + (size_t)s3 * 128);
      float2 v4 = *(const float2*)(base + (size_t)s4 * 128);
      float2 v5 = *(const float2*)(base + (size_t)s5 * 128);
      float2 v6 = *(const float2*)(base + (size_t)s6 * 128);
      float2 v7 = *(const float2*)(base + (size_t)s7 * 128);
      ax += v0.x; ay += v0.y; ax += v1.x; ay += v1.y;
      ax += v2.x; ay += v2.y; ax += v3.x; ay += v3.y;
      ax += v4.x; ay += v4.y; ax += v5.x; ay += v5.y;
      ax += v6.x; ay += v6.y; ax += v7.x; ay += v7.y;
    }
    if (j + 4 <= m){
      int s0 = __shfl(sl, j), s1 = __shfl(sl, j + 1), s2 = __shfl(sl, j + 2), s3 = __shfl(sl, j + 3);
      float2 v0 = *(const float2*)(base + (size_t)s0 * 128);
      float2 v1 = *(const float2*)(base + (size_t)s1 * 128);
      float2 v2 = *(const float2*)(base + (size_t)s2 * 128);
      float2 v3 = *(const float2*)(base + (size_t)s3 * 128);
      ax += v0.x; ay += v0.y; ax += v1.x; ay += v1.y;
      ax += v2.x; ay += v2.y; ax += v3.x; ay += v3.y;
      j += 4;
    }
    for (; j < m; ++j){
      int s = __shfl(sl, j);
      float2 v = *(const float2*)(base + (size_t)s * 128);
      ax += v.x; ay += v.y;
    }
  }
  float di = dinv[gw];
  float2 vs = *(const float2*)(base + (size_t)gw * 128);   // self term: hw'[d] (already * dinv[d])
  ax = (ax + vs.x) * di;
  ay = (ay + vs.y) * di;
  ax = tanhf(ax + bias[f]);
  ay = tanhf(ay + bias[f + 1]);
  f2v r; r.x = ax; r.y = ay;
  __builtin_nontemporal_store(r, (f2v*)(hout + (size_t)gw * 128 + f));
}

// ---------------- pool: stage 1 partial max/sum (G*PSPLIT blocks) ----------------

__global__ __launch_bounds__(256) void k_pool1(const float* __restrict__ h, const int* __restrict__ gstart,
                                               float* __restrict__ pmx, float* __restrict__ psm){
  int g = blockIdx.x >> 3, s = blockIdx.x & (PSPLIT - 1);
  int t = threadIdx.x, f = t & 127, half = t >> 7;
  int i0 = gstart[g], i1 = gstart[g + 1];
  int len = i1 - i0;
  int chunk = (len + PSPLIT - 1) / PSPLIT;
  int a = i0 + s * chunk;
  int b = a + chunk; if (b > i1) b = i1;

  float mx = -INFINITY, sm = 0.f;
  for (int i = a + half; i < b; i += 2){
    float v = h[(size_t)i * 128 + f];
    mx = fmaxf(mx, v); sm += v;
  }
  __shared__ float smx[128], ssm[128];
  if (half){ smx[f] = mx; ssm[f] = sm; }
  __syncthreads();
  if (!half){
    mx = fmaxf(mx, smx[f]); sm += ssm[f];
    pmx[(size_t)blockIdx.x * 128 + f] = mx;
    psm[(size_t)blockIdx.x * 128 + f] = sm;
  }
}

// ---------------- pool stage 2 + linear head (G blocks of 128) ----------------

__global__ __launch_bounds__(128) void k_head(const float* __restrict__ pmx, const float* __restrict__ psm,
                                              const int* __restrict__ gstart,
                                              const float* __restrict__ Wl, const float* __restrict__ bl,
                                              float* __restrict__ out){
  int g = blockIdx.x, f = threadIdx.x;
  float mx = -INFINITY, sm = 0.f;
  #pragma unroll
  for (int s = 0; s < PSPLIT; ++s){
    mx = fmaxf(mx, pmx[((size_t)g * PSPLIT + s) * 128 + f]);
    sm += psm[((size_t)g * PSPLIT + s) * 128 + f];
  }
  int cnt = gstart[g + 1] - gstart[g];
  if (cnt <= 0) mx = 0.f;
  float mn = sm / (float)(cnt > 0 ? cnt : 1);
  float contrib = mx * Wl[f] + mn * Wl[128 + f];
  for (int o = 32; o > 0; o >>= 1) contrib += __shfl_down(contrib, o);
  __shared__ float sred[2];
  if ((f & 63) == 0) sred[f >> 6] = contrib;
  __syncthreads();
  if (f == 0) out[g] = sred[0] + sred[1] + bl[0];
}

// ---------------- launch ----------------

extern "C" void kernel_launch(void* const* d_in, const int* in_sizes, int n_in,
                              void* d_out, int out_size, void* d_ws, size_t ws_size,
                              hipStream_t stream){
  const float* x     = (const float*)d_in[0];
  const int*   ei    = (const int*)d_in[1];
  const int*   batch = (const int*)d_in[2];
  const float* W[4]  = {(const float*)d_in[3], (const float*)d_in[5], (const float*)d_in[7], (const float*)d_in[9]};
  const float* B[4]  = {(const float*)d_in[4], (const float*)d_in[6], (const float*)d_in[8], (const float*)d_in[10]};
  const float* Wl    = (const float*)d_in[11];
  const float* bl    = (const float*)d_in[12];
  float* out = (float*)d_out;

  int N = in_sizes[0] / 128;
  int E = in_sizes[1] / 2;
  int G = out_size;

  char* ws = (char*)d_ws;
  size_t off = 0;
  auto alloc = [&](size_t bytes) -> void* {
    void* p = ws + off; off = align_up(off + bytes, 256); return p;
  };
  int*   deg   = (int*)  alloc((size_t)N * 4);
  float* dinv  = (float*)alloc((size_t)N * 4);
  int*   rp    = (int*)  alloc((size_t)(N + 1) * 4);
  int*   fill  = (int*)  alloc((size_t)N * 4);
  int nch = (N + CHUNK - 1) / CHUNK;
  int*   csum  = (int*)  alloc((size_t)nch * 4);
  int*   coff  = (int*)  alloc((size_t)nch * 4);
  int*   gst   = (int*)  alloc((size_t)(G + 1) * 4);
  int*   ssrc  = (int*)  alloc((size_t)E * 4);
  float* pmx   = (float*)alloc((size_t)G * PSPLIT * 128 * 4);
  float* psm   = (float*)alloc((size_t)G * PSPLIT * 128 * 4);
  float* hw    = (float*)alloc((size_t)N * 128 * 4);
  float* h     = (float*)alloc((size_t)N * 128 * 4);

  hipMemsetAsync(deg, 0, (size_t)N * 4, stream);

  int gE = (E + 255) / 256, gN = (N + 255) / 256;
  k_hist <<<gE, 256, 0, stream>>>(ei + E, deg, E);
  k_dinv <<<gN, 256, 0, stream>>>(deg, dinv, N);
  k_scan1<<<nch, 256, 0, stream>>>(deg, csum, N);
  k_scan2<<<1, 64, 0, stream>>>(csum, coff, nch, rp, N, E);
  k_scan3<<<nch, 256, 0, stream>>>(deg, coff, rp, fill, N);
  k_scatter<<<gE, 256, 0, stream>>>(ei, fill, ssrc, E);
  k_gstart <<<gN, 256, 0, stream>>>(batch, gst, N, G);

  int gemmG = (N + 127) / 128;
  int aggG  = (N + 3) / 4;
  const float* hin = x;
  for (int l = 0; l < 4; ++l){
    k_gemm<<<gemmG, 256, 0, stream>>>(hin, W[l], dinv, hw, N);
    k_agg <<<aggG, 256, 0, stream>>>(hw, rp, ssrc, dinv, B[l], h, N);
    hin = h;
  }
  k_pool1<<<G * PSPLIT, 256, 0, stream>>>(h, gst, pmx, psm);
  k_head <<<G, 128, 0, stream>>>(pmx, psm, gst, Wl, bl, out);
}

// Round 3
// 946.937 us; speedup vs baseline: 1.1943x; 1.0849x over previous
//
#include <hip/hip_runtime.h>
#include <math.h>

#define PSPLIT 8
#define BSH 5                  // bucket = dst >> BSH  (32 dsts/bucket)
#define BW 32

typedef float f4v __attribute__((ext_vector_type(4)));

static inline size_t align_up(size_t x, size_t a){ return (x + a - 1) & ~(a - 1); }

// ---------------- graph prep: bucketed CSR build ----------------

__global__ __launch_bounds__(256) void k_bhist(const int* __restrict__ col, int* __restrict__ bcnt,
                                               int E, int NB){
  extern __shared__ int lh[];
  for (int i = threadIdx.x; i < NB; i += 256) lh[i] = 0;
  __syncthreads();
  for (int e = blockIdx.x * 256 + threadIdx.x; e < E; e += gridDim.x * 256)
    atomicAdd(&lh[col[e] >> BSH], 1);
  __syncthreads();
  for (int i = threadIdx.x; i < NB; i += 256){
    int v = lh[i];
    if (v) atomicAdd(&bcnt[i], v);
  }
}

__global__ void k_bscan(const int* __restrict__ bcnt, int* __restrict__ boff, int NB, int E,
                        int* __restrict__ rp, int N){
  __shared__ int sd[256];
  int t = threadIdx.x;
  int c[16]; int s = 0;
  const int PT = (NB + 255) / 256;   // <= 16
  for (int j = 0; j < PT; ++j){ int i = t * PT + j; c[j] = (i < NB) ? bcnt[i] : 0; s += c[j]; }
  sd[t] = s; __syncthreads();
  for (int off = 1; off < 256; off <<= 1){
    int v = sd[t];
    if (t >= off) v += sd[t - off];
    __syncthreads(); sd[t] = v; __syncthreads();
  }
  int run = sd[t] - s;
  for (int j = 0; j < PT; ++j){ int i = t * PT + j; if (i < NB) boff[i] = run; run += c[j]; }
  if (t == 255){ boff[NB] = run; rp[N] = E; }
}

__global__ __launch_bounds__(256) void k_bscat(const int* __restrict__ ei, const int* __restrict__ boff,
                                               int* __restrict__ bfill, unsigned* __restrict__ tmp, int E){
  int e = blockIdx.x * 256 + threadIdx.x;
  if (e >= E) return;
  int s = ei[e], d = ei[E + e];
  int b = d >> BSH;
  int p = atomicAdd(&bfill[b * 16], 1);          // line-padded counter
  tmp[boff[b] + p] = (unsigned)s | ((unsigned)(d & (BW - 1)) << 17);
}

__global__ __launch_bounds__(256) void k_bfin(const unsigned* __restrict__ tmp, const int* __restrict__ boff,
                                              int* __restrict__ ssrc, int* __restrict__ rp,
                                              int* __restrict__ deg, int N){
  int b = blockIdx.x;
  int d0 = b << BSH;
  int lim = N - d0; if (lim > BW) lim = BW;
  __shared__ int dcnt[BW], dst_[BW], lfill[BW];
  int t = threadIdx.x;
  if (t < BW){ dcnt[t] = 0; lfill[t] = 0; }
  __syncthreads();
  int lo = boff[b], hi = boff[b + 1];
  for (int i = lo + t; i < hi; i += 256) atomicAdd(&dcnt[tmp[i] >> 17], 1);
  __syncthreads();
  if (t == 0){ int run = 0; for (int l = 0; l < BW; ++l){ dst_[l] = run; run += dcnt[l]; } }
  __syncthreads();
  if (t < lim){ int d = d0 + t; rp[d] = lo + dst_[t]; deg[d] = dcnt[t]; }
  __syncthreads();
  for (int i = lo + t; i < hi; i += 256){
    unsigned r = tmp[i];
    int l = r >> 17;
    int pos = dst_[l] + atomicAdd(&lfill[l], 1);
    ssrc[lo + pos] = (int)(r & 0x1FFFFu);
  }
}

__global__ __launch_bounds__(256) void k_dinv(const int* __restrict__ cnt, float* __restrict__ dinv, int n){
  int i = blockIdx.x * 256 + threadIdx.x;
  if (i < n){
    double d = (double)(cnt[i] + 1);          // +1 self-loop
    dinv[i] = (float)(1.0 / sqrt(d));
  }
}

__global__ __launch_bounds__(256) void k_gstart(const int* __restrict__ batch, int* __restrict__ gstart,
                                                int n, int G){
  int i = blockIdx.x * 256 + threadIdx.x;
  if (i >= n) return;
  int cb = batch[i];
  if (i == 0){ for (int g = 0; g <= cb; ++g) gstart[g] = 0; }
  else { int pb = batch[i - 1]; for (int g = pb + 1; g <= cb; ++g) gstart[g] = i; }
  if (i == n - 1){ for (int g = cb + 1; g <= G; ++g) gstart[g] = n; }
}

// ---------------- GEMM: C[N,128] = (A[N,128] @ W[128,128]) * dinv[row] ----------------

__global__ __launch_bounds__(256, 2) void k_gemm(const float* __restrict__ A, const float* __restrict__ W,
                                                 const float* __restrict__ dinv,
                                                 float* __restrict__ C, int n){
  __shared__ __align__(16) float Ws[128 * 128];
  int t = threadIdx.x;
  {
    const float4* Wv = (const float4*)W;
    float4* Sv = (float4*)Ws;
    #pragma unroll
    for (int i = 0; i < 16; ++i) Sv[t + 256 * i] = Wv[t + 256 * i];
  }
  __syncthreads();

  int rg = t >> 4, cg = t & 15;
  int r0 = blockIdx.x * 128 + rg * 8;
  int ca = cg * 4, cb = 64 + cg * 4;

  float4 acc_a[8], acc_b[8];
  #pragma unroll
  for (int j = 0; j < 8; ++j){ acc_a[j] = make_float4(0,0,0,0); acc_b[j] = make_float4(0,0,0,0); }

  size_t rowp[8];
  #pragma unroll
  for (int j = 0; j < 8; ++j){
    int rr = r0 + j; if (rr > n - 1) rr = n - 1;
    rowp[j] = (size_t)rr * 128;
  }

  #pragma unroll 2
  for (int k4 = 0; k4 < 128; k4 += 4){
    float4 a[8];
    #pragma unroll
    for (int j = 0; j < 8; ++j) a[j] = *(const float4*)(A + rowp[j] + k4);
    #pragma unroll
    for (int q = 0; q < 4; ++q){
      float4 wa = *(const float4*)(Ws + (k4 + q) * 128 + ca);
      float4 wb = *(const float4*)(Ws + (k4 + q) * 128 + cb);
      #pragma unroll
      for (int j = 0; j < 8; ++j){
        float av = (q == 0) ? a[j].x : (q == 1) ? a[j].y : (q == 2) ? a[j].z : a[j].w;
        acc_a[j].x += av * wa.x; acc_a[j].y += av * wa.y; acc_a[j].z += av * wa.z; acc_a[j].w += av * wa.w;
        acc_b[j].x += av * wb.x; acc_b[j].y += av * wb.y; acc_b[j].z += av * wb.z; acc_b[j].w += av * wb.w;
      }
    }
  }

  #pragma unroll
  for (int j = 0; j < 8; ++j){
    int rr = r0 + j;
    if (rr < n){
      float sc = dinv[rr];
      float4 va = acc_a[j], vb = acc_b[j];
      va.x *= sc; va.y *= sc; va.z *= sc; va.w *= sc;
      vb.x *= sc; vb.y *= sc; vb.z *= sc; vb.w *= sc;
      *(float4*)(C + (size_t)rr * 128 + ca) = va;
      *(float4*)(C + (size_t)rr * 128 + cb) = vb;
    }
  }
}

// ---------------- aggregate: h_out = tanh(dinv[d]*(sum hw'[src] + hw'[d]) + b) ----------------
// one wave per node; HALF-wave per edge row (float4/lane, 16B = coalescing sweet spot),
// 2 edges in flight per vector instruction, 16-edge unrolled head (8 outstanding loads).

__global__ __launch_bounds__(256) void k_agg(const float* __restrict__ hwp, const int* __restrict__ rp,
                                             const int* __restrict__ ssrc,
                                             const float* __restrict__ dinv, const float* __restrict__ bias,
                                             float* __restrict__ hout, int n){
  int gw = (blockIdx.x * 256 + threadIdx.x) >> 6;
  if (gw >= n) return;
  int lane = threadIdx.x & 63;
  int hl = lane >> 5;            // which edge of the pair
  int fl = lane & 31;            // feature quad
  const float4* base = (const float4*)hwp + fl;

  int e0 = rp[gw], e1 = rp[gw + 1];
  float4 acc = make_float4(0, 0, 0, 0);
  for (int eb = e0; eb < e1; eb += 64){
    int m = e1 - eb; if (m > 64) m = 64;
    int sl = (lane < m) ? ssrc[eb + lane] : 0;
    int mp = m & ~1;
    int j = 0;
    for (; j + 16 <= mp; j += 16){
      int s0 = __shfl(sl, j + hl),      s1 = __shfl(sl, j + 2 + hl);
      int s2 = __shfl(sl, j + 4 + hl),  s3 = __shfl(sl, j + 6 + hl);
      int s4 = __shfl(sl, j + 8 + hl),  s5 = __shfl(sl, j + 10 + hl);
      int s6 = __shfl(sl, j + 12 + hl), s7 = __shfl(sl, j + 14 + hl);
      float4 v0 = base[(size_t)s0 * 32], v1 = base[(size_t)s1 * 32];
      float4 v2 = base[(size_t)s2 * 32], v3 = base[(size_t)s3 * 32];
      float4 v4 = base[(size_t)s4 * 32], v5 = base[(size_t)s5 * 32];
      float4 v6 = base[(size_t)s6 * 32], v7 = base[(size_t)s7 * 32];
      acc.x += v0.x; acc.y += v0.y; acc.z += v0.z; acc.w += v0.w;
      acc.x += v1.x; acc.y += v1.y; acc.z += v1.z; acc.w += v1.w;
      acc.x += v2.x; acc.y += v2.y; acc.z += v2.z; acc.w += v2.w;
      acc.x += v3.x; acc.y += v3.y; acc.z += v3.z; acc.w += v3.w;
      acc.x += v4.x; acc.y += v4.y; acc.z += v4.z; acc.w += v4.w;
      acc.x += v5.x; acc.y += v5.y; acc.z += v5.z; acc.w += v5.w;
      acc.x += v6.x; acc.y += v6.y; acc.z += v6.z; acc.w += v6.w;
      acc.x += v7.x; acc.y += v7.y; acc.z += v7.z; acc.w += v7.w;
    }
    if (j + 8 <= mp){
      int s0 = __shfl(sl, j + hl),     s1 = __shfl(sl, j + 2 + hl);
      int s2 = __shfl(sl, j + 4 + hl), s3 = __shfl(sl, j + 6 + hl);
      float4 v0 = base[(size_t)s0 * 32], v1 = base[(size_t)s1 * 32];
      float4 v2 = base[(size_t)s2 * 32], v3 = base[(size_t)s3 * 32];
      acc.x += v0.x; acc.y += v0.y; acc.z += v0.z; acc.w += v0.w;
      acc.x += v1.x; acc.y += v1.y; acc.z += v1.z; acc.w += v1.w;
      acc.x += v2.x; acc.y += v2.y; acc.z += v2.z; acc.w += v2.w;
      acc.x += v3.x; acc.y += v3.y; acc.z += v3.z; acc.w += v3.w;
      j += 8;
    }
    if (j + 4 <= mp){
      int s0 = __shfl(sl, j + hl), s1 = __shfl(sl, j + 2 + hl);
      float4 v0 = base[(size_t)s0 * 32], v1 = base[(size_t)s1 * 32];
      acc.x += v0.x; acc.y += v0.y; acc.z += v0.z; acc.w += v0.w;
      acc.x += v1.x; acc.y += v1.y; acc.z += v1.z; acc.w += v1.w;
      j += 4;
    }
    if (j + 2 <= mp){
      int s0 = __shfl(sl, j + hl);
      float4 v0 = base[(size_t)s0 * 32];
      acc.x += v0.x; acc.y += v0.y; acc.z += v0.z; acc.w += v0.w;
      j += 2;
    }
    if (m & 1){
      int s0 = __shfl(sl, m - 1);
      if (hl == 0){
        float4 v0 = base[(size_t)s0 * 32];
        acc.x += v0.x; acc.y += v0.y; acc.z += v0.z; acc.w += v0.w;
      }
    }
  }
  if (hl == 0){                       // self term: hw'[d] (already * dinv[d])
    float4 vs = base[(size_t)gw * 32];
    acc.x += vs.x; acc.y += vs.y; acc.z += vs.z; acc.w += vs.w;
  }
  acc.x += __shfl_down(acc.x, 32);
  acc.y += __shfl_down(acc.y, 32);
  acc.z += __shfl_down(acc.z, 32);
  acc.w += __shfl_down(acc.w, 32);
  if (hl == 0){
    float di = dinv[gw];
    int f = fl * 4;
    float4 bv = *(const float4*)(bias + f);
    f4v r;
    r.x = tanhf(acc.x * di + bv.x);
    r.y = tanhf(acc.y * di + bv.y);
    r.z = tanhf(acc.z * di + bv.z);
    r.w = tanhf(acc.w * di + bv.w);
    __builtin_nontemporal_store(r, (f4v*)(hout + (size_t)gw * 128 + f));
  }
}

// ---------------- pool: stage 1 partial max/sum ----------------

__global__ __launch_bounds__(256) void k_pool1(const float* __restrict__ h, const int* __restrict__ gstart,
                                               float* __restrict__ pmx, float* __restrict__ psm){
  int g = blockIdx.x >> 3, s = blockIdx.x & (PSPLIT - 1);
  int t = threadIdx.x, f = t & 127, half = t >> 7;
  int i0 = gstart[g], i1 = gstart[g + 1];
  int len = i1 - i0;
  int chunk = (len + PSPLIT - 1) / PSPLIT;
  int a = i0 + s * chunk;
  int b = a + chunk; if (b > i1) b = i1;

  float mx = -INFINITY, sm = 0.f;
  for (int i = a + half; i < b; i += 2){
    float v = h[(size_t)i * 128 + f];
    mx = fmaxf(mx, v); sm += v;
  }
  __shared__ float smx[128], ssm[128];
  if (half){ smx[f] = mx; ssm[f] = sm; }
  __syncthreads();
  if (!half){
    mx = fmaxf(mx, smx[f]); sm += ssm[f];
    pmx[(size_t)blockIdx.x * 128 + f] = mx;
    psm[(size_t)blockIdx.x * 128 + f] = sm;
  }
}

__global__ __launch_bounds__(128) void k_head(const float* __restrict__ pmx, const float* __restrict__ psm,
                                              const int* __restrict__ gstart,
                                              const float* __restrict__ Wl, const float* __restrict__ bl,
                                              float* __restrict__ out){
  int g = blockIdx.x, f = threadIdx.x;
  float mx = -INFINITY, sm = 0.f;
  #pragma unroll
  for (int s = 0; s < PSPLIT; ++s){
    mx = fmaxf(mx, pmx[((size_t)g * PSPLIT + s) * 128 + f]);
    sm += psm[((size_t)g * PSPLIT + s) * 128 + f];
  }
  int cnt = gstart[g + 1] - gstart[g];
  if (cnt <= 0) mx = 0.f;
  float mn = sm / (float)(cnt > 0 ? cnt : 1);
  float contrib = mx * Wl[f] + mn * Wl[128 + f];
  for (int o = 32; o > 0; o >>= 1) contrib += __shfl_down(contrib, o);
  __shared__ float sred[2];
  if ((f & 63) == 0) sred[f >> 6] = contrib;
  __syncthreads();
  if (f == 0) out[g] = sred[0] + sred[1] + bl[0];
}

// ---------------- launch ----------------

extern "C" void kernel_launch(void* const* d_in, const int* in_sizes, int n_in,
                              void* d_out, int out_size, void* d_ws, size_t ws_size,
                              hipStream_t stream){
  const float* x     = (const float*)d_in[0];
  const int*   ei    = (const int*)d_in[1];
  const int*   batch = (const int*)d_in[2];
  const float* W[4]  = {(const float*)d_in[3], (const float*)d_in[5], (const float*)d_in[7], (const float*)d_in[9]};
  const float* B[4]  = {(const float*)d_in[4], (const float*)d_in[6], (const float*)d_in[8], (const float*)d_in[10]};
  const float* Wl    = (const float*)d_in[11];
  const float* bl    = (const float*)d_in[12];
  float* out = (float*)d_out;

  int N = in_sizes[0] / 128;
  int E = in_sizes[1] / 2;
  int G = out_size;
  int NB = (N + BW - 1) >> BSH;

  char* ws = (char*)d_ws;
  size_t off = 0;
  auto alloc = [&](size_t bytes) -> void* {
    void* p = ws + off; off = align_up(off + bytes, 256); return p;
  };
  int*   deg   = (int*)  alloc((size_t)N * 4);
  float* dinv  = (float*)alloc((size_t)N * 4);
  int*   rp    = (int*)  alloc((size_t)(N + 1) * 4);
  int*   bcnt  = (int*)  alloc((size_t)(NB + 1) * 4);
  int*   boff  = (int*)  alloc((size_t)(NB + 1) * 4);
  int*   bfill = (int*)  alloc((size_t)NB * 16 * 4);
  int*   gst   = (int*)  alloc((size_t)(G + 1) * 4);
  int*   ssrc  = (int*)  alloc((size_t)E * 4);
  float* pmx   = (float*)alloc((size_t)G * PSPLIT * 128 * 4);
  float* psm   = (float*)alloc((size_t)G * PSPLIT * 128 * 4);
  float* hw    = (float*)alloc((size_t)N * 128 * 4);
  float* h     = (float*)alloc((size_t)N * 128 * 4);
  unsigned* tmp = (unsigned*)hw;   // alias: tmp dead before first gemm writes hw

  hipMemsetAsync(bcnt, 0, (size_t)(NB + 1) * 4, stream);
  hipMemsetAsync(bfill, 0, (size_t)NB * 16 * 4, stream);

  int gE = (E + 255) / 256, gN = (N + 255) / 256;
  k_bhist<<<128, 256, NB * 4, stream>>>(ei + E, bcnt, E, NB);
  k_bscan<<<1, 256, 0, stream>>>(bcnt, boff, NB, E, rp, N);
  k_bscat<<<gE, 256, 0, stream>>>(ei, boff, bfill, tmp, E);
  k_bfin <<<NB, 256, 0, stream>>>(tmp, boff, ssrc, rp, deg, N);
  k_dinv <<<gN, 256, 0, stream>>>(deg, dinv, N);
  k_gstart<<<gN, 256, 0, stream>>>(batch, gst, N, G);

  int gemmG = (N + 127) / 128;
  int aggG  = (N + 3) / 4;
  const float* hin = x;
  for (int l = 0; l < 4; ++l){
    k_gemm<<<gemmG, 256, 0, stream>>>(hin, W[l], dinv, hw, N);
    k_agg <<<aggG, 256, 0, stream>>>(hw, rp, ssrc, dinv, B[l], h, N);
    hin = h;
  }
  k_pool1<<<G * PSPLIT, 256, 0, stream>>>(h, gst, pmx, psm);
  k_head <<<G, 128, 0, stream>>>(pmx, psm, gst, Wl, bl, out);
}

// Round 4
// 909.622 us; speedup vs baseline: 1.2433x; 1.0410x over previous
//
#include <hip/hip_runtime.h>
#include <math.h>

#define PSPLIT 8
#define BSH 5                  // bucket = dst >> BSH  (32 dsts/bucket)
#define BW 32

typedef float f4v __attribute__((ext_vector_type(4)));

static inline size_t align_up(size_t x, size_t a){ return (x + a - 1) & ~(a - 1); }

// ---------------- graph prep: bucketed CSR build ----------------
// also computes gstart (fused, grid-stride) to save a launch

__global__ __launch_bounds__(256) void k_bhist(const int* __restrict__ col, int* __restrict__ bcnt,
                                               int E, int NB,
                                               const int* __restrict__ batch, int* __restrict__ gstart,
                                               int n, int G){
  extern __shared__ int lh[];
  for (int i = threadIdx.x; i < NB; i += 256) lh[i] = 0;
  __syncthreads();
  for (int e = blockIdx.x * 256 + threadIdx.x; e < E; e += gridDim.x * 256)
    atomicAdd(&lh[col[e] >> BSH], 1);
  __syncthreads();
  for (int i = threadIdx.x; i < NB; i += 256){
    int v = lh[i];
    if (v) atomicAdd(&bcnt[i], v);
  }
  // fused gstart
  for (int i = blockIdx.x * 256 + threadIdx.x; i < n; i += gridDim.x * 256){
    int cb = batch[i];
    if (i == 0){ for (int g = 0; g <= cb; ++g) gstart[g] = 0; }
    else { int pb = batch[i - 1]; for (int g = pb + 1; g <= cb; ++g) gstart[g] = i; }
    if (i == n - 1){ for (int g = cb + 1; g <= G; ++g) gstart[g] = n; }
  }
}

__global__ void k_bscan(const int* __restrict__ bcnt, int* __restrict__ boff, int NB, int E,
                        int* __restrict__ rp, int N){
  __shared__ int sd[256];
  int t = threadIdx.x;
  int c[16]; int s = 0;
  const int PT = (NB + 255) / 256;   // <= 16
  for (int j = 0; j < PT; ++j){ int i = t * PT + j; c[j] = (i < NB) ? bcnt[i] : 0; s += c[j]; }
  sd[t] = s; __syncthreads();
  for (int off = 1; off < 256; off <<= 1){
    int v = sd[t];
    if (t >= off) v += sd[t - off];
    __syncthreads(); sd[t] = v; __syncthreads();
  }
  int run = sd[t] - s;
  for (int j = 0; j < PT; ++j){ int i = t * PT + j; if (i < NB) boff[i] = run; run += c[j]; }
  if (t == 255){ boff[NB] = run; rp[N] = E; }
}

__global__ __launch_bounds__(256) void k_bscat(const int* __restrict__ ei, const int* __restrict__ boff,
                                               int* __restrict__ bfill, unsigned* __restrict__ tmp, int E){
  int e = blockIdx.x * 256 + threadIdx.x;
  if (e >= E) return;
  int s = ei[e], d = ei[E + e];
  int b = d >> BSH;
  int p = atomicAdd(&bfill[b * 16], 1);          // line-padded counter
  tmp[boff[b] + p] = (unsigned)s | ((unsigned)(d & (BW - 1)) << 17);
}

__global__ __launch_bounds__(256) void k_bfin(const unsigned* __restrict__ tmp, const int* __restrict__ boff,
                                              int* __restrict__ ssrc, int* __restrict__ rp,
                                              float* __restrict__ dinv, int N){
  int b = blockIdx.x;
  int d0 = b << BSH;
  int lim = N - d0; if (lim > BW) lim = BW;
  __shared__ int dcnt[BW], dst_[BW], lfill[BW];
  int t = threadIdx.x;
  if (t < BW){ dcnt[t] = 0; lfill[t] = 0; }
  __syncthreads();
  int lo = boff[b], hi = boff[b + 1];
  for (int i = lo + t; i < hi; i += 256) atomicAdd(&dcnt[tmp[i] >> 17], 1);
  __syncthreads();
  if (t == 0){ int run = 0; for (int l = 0; l < BW; ++l){ dst_[l] = run; run += dcnt[l]; } }
  __syncthreads();
  if (t < lim){
    int d = d0 + t;
    rp[d] = lo + dst_[t];
    double dd = (double)(dcnt[t] + 1);           // +1 self-loop
    dinv[d] = (float)(1.0 / sqrt(dd));
  }
  __syncthreads();
  for (int i = lo + t; i < hi; i += 256){
    unsigned r = tmp[i];
    int l = r >> 17;
    int pos = dst_[l] + atomicAdd(&lfill[l], 1);
    ssrc[lo + pos] = (int)(r & 0x1FFFFu);
  }
}

// ---------------- GEMM: C[N,128] = (A[N,128] @ W[128,128]) * dinv[row] ----------------
// 128x128 tile, 256 threads, 8x8 register tile. k-sliced LDS (16 k's at a time):
// As[k][row] (transposed at stage) + Ws[k][col]. 16 KB LDS -> 4 blocks/CU.
// Inner loop: per k = 4x ds_read_b128 : 64 FMA -> VALU-bound.

__global__ __launch_bounds__(256, 4) void k_gemm(const float* __restrict__ A, const float* __restrict__ W,
                                                 const float* __restrict__ dinv,
                                                 float* __restrict__ C, int n){
  __shared__ __align__(16) float As[16][128];
  __shared__ __align__(16) float Ws[16][128];
  int t = threadIdx.x;
  int rg = t >> 4, cg = t & 15;
  int r0 = blockIdx.x * 128;
  int ra = rg * 8;
  int ca = cg * 4, cb = 64 + cg * 4;

  // staging indices
  int srow = t >> 1;               // 0..127
  int shalf = (t & 1) * 8;         // 0 or 8
  int grow = r0 + srow; if (grow > n - 1) grow = n - 1;
  const float* ga = A + (size_t)grow * 128 + shalf;

  float4 acc_a[8], acc_b[8];
  #pragma unroll
  for (int j = 0; j < 8; ++j){ acc_a[j] = make_float4(0,0,0,0); acc_b[j] = make_float4(0,0,0,0); }

  for (int k0 = 0; k0 < 128; k0 += 16){
    // stage A (transpose) + W
    float4 a0 = *(const float4*)(ga + k0);
    float4 a1 = *(const float4*)(ga + k0 + 4);
    const float4* wsrc = (const float4*)(W + (size_t)k0 * 128);
    float4 w0 = wsrc[t * 2], w1 = wsrc[t * 2 + 1];
    __syncthreads();
    As[shalf + 0][srow] = a0.x; As[shalf + 1][srow] = a0.y;
    As[shalf + 2][srow] = a0.z; As[shalf + 3][srow] = a0.w;
    As[shalf + 4][srow] = a1.x; As[shalf + 5][srow] = a1.y;
    As[shalf + 6][srow] = a1.z; As[shalf + 7][srow] = a1.w;
    ((float4*)Ws)[t * 2] = w0; ((float4*)Ws)[t * 2 + 1] = w1;
    __syncthreads();

    #pragma unroll
    for (int k = 0; k < 16; ++k){
      float4 av0 = *(const float4*)&As[k][ra];
      float4 av1 = *(const float4*)&As[k][ra + 4];
      float4 wa  = *(const float4*)&Ws[k][ca];
      float4 wb  = *(const float4*)&Ws[k][cb];
      float av[8] = {av0.x, av0.y, av0.z, av0.w, av1.x, av1.y, av1.z, av1.w};
      #pragma unroll
      for (int j = 0; j < 8; ++j){
        acc_a[j].x += av[j] * wa.x; acc_a[j].y += av[j] * wa.y;
        acc_a[j].z += av[j] * wa.z; acc_a[j].w += av[j] * wa.w;
        acc_b[j].x += av[j] * wb.x; acc_b[j].y += av[j] * wb.y;
        acc_b[j].z += av[j] * wb.z; acc_b[j].w += av[j] * wb.w;
      }
    }
  }

  #pragma unroll
  for (int j = 0; j < 8; ++j){
    int rr = r0 + ra + j;
    if (rr < n){
      float sc = dinv[rr];
      float4 va = acc_a[j], vb = acc_b[j];
      va.x *= sc; va.y *= sc; va.z *= sc; va.w *= sc;
      vb.x *= sc; vb.y *= sc; vb.z *= sc; vb.w *= sc;
      *(float4*)(C + (size_t)rr * 128 + ca) = va;
      *(float4*)(C + (size_t)rr * 128 + cb) = vb;
    }
  }
}

// ---------------- aggregate: h_out = tanh(dinv[d]*(sum hw'[src] + hw'[d]) + b) ----------------
// one wave per node; half-wave per edge row (float4/lane), 16-edge unrolled head.
// At the fabric roofline (~3.8 TB/s, 8xXCD x 51MB structural fetch) — do not perturb.

__global__ __launch_bounds__(256) void k_agg(const float* __restrict__ hwp, const int* __restrict__ rp,
                                             const int* __restrict__ ssrc,
                                             const float* __restrict__ dinv, const float* __restrict__ bias,
                                             float* __restrict__ hout, int n){
  int gw = (blockIdx.x * 256 + threadIdx.x) >> 6;
  if (gw >= n) return;
  int lane = threadIdx.x & 63;
  int hl = lane >> 5;            // which edge of the pair
  int fl = lane & 31;            // feature quad
  const float4* base = (const float4*)hwp + fl;

  int e0 = rp[gw], e1 = rp[gw + 1];
  float4 acc = make_float4(0, 0, 0, 0);
  for (int eb = e0; eb < e1; eb += 64){
    int m = e1 - eb; if (m > 64) m = 64;
    int sl = (lane < m) ? ssrc[eb + lane] : 0;
    int mp = m & ~1;
    int j = 0;
    for (; j + 16 <= mp; j += 16){
      int s0 = __shfl(sl, j + hl),      s1 = __shfl(sl, j + 2 + hl);
      int s2 = __shfl(sl, j + 4 + hl),  s3 = __shfl(sl, j + 6 + hl);
      int s4 = __shfl(sl, j + 8 + hl),  s5 = __shfl(sl, j + 10 + hl);
      int s6 = __shfl(sl, j + 12 + hl), s7 = __shfl(sl, j + 14 + hl);
      float4 v0 = base[(size_t)s0 * 32], v1 = base[(size_t)s1 * 32];
      float4 v2 = base[(size_t)s2 * 32], v3 = base[(size_t)s3 * 32];
      float4 v4 = base[(size_t)s4 * 32], v5 = base[(size_t)s5 * 32];
      float4 v6 = base[(size_t)s6 * 32], v7 = base[(size_t)s7 * 32];
      acc.x += v0.x; acc.y += v0.y; acc.z += v0.z; acc.w += v0.w;
      acc.x += v1.x; acc.y += v1.y; acc.z += v1.z; acc.w += v1.w;
      acc.x += v2.x; acc.y += v2.y; acc.z += v2.z; acc.w += v2.w;
      acc.x += v3.x; acc.y += v3.y; acc.z += v3.z; acc.w += v3.w;
      acc.x += v4.x; acc.y += v4.y; acc.z += v4.z; acc.w += v4.w;
      acc.x += v5.x; acc.y += v5.y; acc.z += v5.z; acc.w += v5.w;
      acc.x += v6.x; acc.y += v6.y; acc.z += v6.z; acc.w += v6.w;
      acc.x += v7.x; acc.y += v7.y; acc.z += v7.z; acc.w += v7.w;
    }
    if (j + 8 <= mp){
      int s0 = __shfl(sl, j + hl),     s1 = __shfl(sl, j + 2 + hl);
      int s2 = __shfl(sl, j + 4 + hl), s3 = __shfl(sl, j + 6 + hl);
      float4 v0 = base[(size_t)s0 * 32], v1 = base[(size_t)s1 * 32];
      float4 v2 = base[(size_t)s2 * 32], v3 = base[(size_t)s3 * 32];
      acc.x += v0.x; acc.y += v0.y; acc.z += v0.z; acc.w += v0.w;
      acc.x += v1.x; acc.y += v1.y; acc.z += v1.z; acc.w += v1.w;
      acc.x += v2.x; acc.y += v2.y; acc.z += v2.z; acc.w += v2.w;
      acc.x += v3.x; acc.y += v3.y; acc.z += v3.z; acc.w += v3.w;
      j += 8;
    }
    if (j + 4 <= mp){
      int s0 = __shfl(sl, j + hl), s1 = __shfl(sl, j + 2 + hl);
      float4 v0 = base[(size_t)s0 * 32], v1 = base[(size_t)s1 * 32];
      acc.x += v0.x; acc.y += v0.y; acc.z += v0.z; acc.w += v0.w;
      acc.x += v1.x; acc.y += v1.y; acc.z += v1.z; acc.w += v1.w;
      j += 4;
    }
    if (j + 2 <= mp){
      int s0 = __shfl(sl, j + hl);
      float4 v0 = base[(size_t)s0 * 32];
      acc.x += v0.x; acc.y += v0.y; acc.z += v0.z; acc.w += v0.w;
      j += 2;
    }
    if (m & 1){
      int s0 = __shfl(sl, m - 1);
      if (hl == 0){
        float4 v0 = base[(size_t)s0 * 32];
        acc.x += v0.x; acc.y += v0.y; acc.z += v0.z; acc.w += v0.w;
      }
    }
  }
  if (hl == 0){                       // self term: hw'[d] (already * dinv[d])
    float4 vs = base[(size_t)gw * 32];
    acc.x += vs.x; acc.y += vs.y; acc.z += vs.z; acc.w += vs.w;
  }
  acc.x += __shfl_down(acc.x, 32);
  acc.y += __shfl_down(acc.y, 32);
  acc.z += __shfl_down(acc.z, 32);
  acc.w += __shfl_down(acc.w, 32);
  if (hl == 0){
    float di = dinv[gw];
    int f = fl * 4;
    float4 bv = *(const float4*)(bias + f);
    f4v r;
    r.x = tanhf(acc.x * di + bv.x);
    r.y = tanhf(acc.y * di + bv.y);
    r.z = tanhf(acc.z * di + bv.z);
    r.w = tanhf(acc.w * di + bv.w);
    __builtin_nontemporal_store(r, (f4v*)(hout + (size_t)gw * 128 + f));
  }
}

// ---------------- pool: stage 1 partial max/sum ----------------

__global__ __launch_bounds__(256) void k_pool1(const float* __restrict__ h, const int* __restrict__ gstart,
                                               float* __restrict__ pmx, float* __restrict__ psm){
  int g = blockIdx.x >> 3, s = blockIdx.x & (PSPLIT - 1);
  int t = threadIdx.x, f = t & 127, half = t >> 7;
  int i0 = gstart[g], i1 = gstart[g + 1];
  int len = i1 - i0;
  int chunk = (len + PSPLIT - 1) / PSPLIT;
  int a = i0 + s * chunk;
  int b = a + chunk; if (b > i1) b = i1;

  float mx = -INFINITY, sm = 0.f;
  for (int i = a + half; i < b; i += 2){
    float v = h[(size_t)i * 128 + f];
    mx = fmaxf(mx, v); sm += v;
  }
  __shared__ float smx[128], ssm[128];
  if (half){ smx[f] = mx; ssm[f] = sm; }
  __syncthreads();
  if (!half){
    mx = fmaxf(mx, smx[f]); sm += ssm[f];
    pmx[(size_t)blockIdx.x * 128 + f] = mx;
    psm[(size_t)blockIdx.x * 128 + f] = sm;
  }
}

__global__ __launch_bounds__(128) void k_head(const float* __restrict__ pmx, const float* __restrict__ psm,
                                              const int* __restrict__ gstart,
                                              const float* __restrict__ Wl, const float* __restrict__ bl,
                                              float* __restrict__ out){
  int g = blockIdx.x, f = threadIdx.x;
  float mx = -INFINITY, sm = 0.f;
  #pragma unroll
  for (int s = 0; s < PSPLIT; ++s){
    mx = fmaxf(mx, pmx[((size_t)g * PSPLIT + s) * 128 + f]);
    sm += psm[((size_t)g * PSPLIT + s) * 128 + f];
  }
  int cnt = gstart[g + 1] - gstart[g];
  if (cnt <= 0) mx = 0.f;
  float mn = sm / (float)(cnt > 0 ? cnt : 1);
  float contrib = mx * Wl[f] + mn * Wl[128 + f];
  for (int o = 32; o > 0; o >>= 1) contrib += __shfl_down(contrib, o);
  __shared__ float sred[2];
  if ((f & 63) == 0) sred[f >> 6] = contrib;
  __syncthreads();
  if (f == 0) out[g] = sred[0] + sred[1] + bl[0];
}

// ---------------- launch ----------------

extern "C" void kernel_launch(void* const* d_in, const int* in_sizes, int n_in,
                              void* d_out, int out_size, void* d_ws, size_t ws_size,
                              hipStream_t stream){
  const float* x     = (const float*)d_in[0];
  const int*   ei    = (const int*)d_in[1];
  const int*   batch = (const int*)d_in[2];
  const float* W[4]  = {(const float*)d_in[3], (const float*)d_in[5], (const float*)d_in[7], (const float*)d_in[9]};
  const float* B[4]  = {(const float*)d_in[4], (const float*)d_in[6], (const float*)d_in[8], (const float*)d_in[10]};
  const float* Wl    = (const float*)d_in[11];
  const float* bl    = (const float*)d_in[12];
  float* out = (float*)d_out;

  int N = in_sizes[0] / 128;
  int E = in_sizes[1] / 2;
  int G = out_size;
  int NB = (N + BW - 1) >> BSH;

  char* ws = (char*)d_ws;
  size_t off = 0;
  auto alloc = [&](size_t bytes) -> void* {
    void* p = ws + off; off = align_up(off + bytes, 256); return p;
  };
  float* dinv  = (float*)alloc((size_t)N * 4);
  int*   rp    = (int*)  alloc((size_t)(N + 1) * 4);
  int*   bcnt  = (int*)  alloc((size_t)(NB + 1) * 4);
  int*   boff  = (int*)  alloc((size_t)(NB + 1) * 4);
  int*   bfill = (int*)  alloc((size_t)NB * 16 * 4);
  int*   gst   = (int*)  alloc((size_t)(G + 1) * 4);
  int*   ssrc  = (int*)  alloc((size_t)E * 4);
  float* pmx   = (float*)alloc((size_t)G * PSPLIT * 128 * 4);
  float* psm   = (float*)alloc((size_t)G * PSPLIT * 128 * 4);
  float* hw    = (float*)alloc((size_t)N * 128 * 4);
  float* h     = (float*)alloc((size_t)N * 128 * 4);
  unsigned* tmp = (unsigned*)hw;   // alias: tmp dead before first gemm writes hw

  hipMemsetAsync(bcnt, 0, (size_t)(NB + 1) * 4, stream);
  hipMemsetAsync(bfill, 0, (size_t)NB * 16 * 4, stream);

  int gE = (E + 255) / 256;
  k_bhist<<<128, 256, NB * 4, stream>>>(ei + E, bcnt, E, NB, batch, gst, N, G);
  k_bscan<<<1, 256, 0, stream>>>(bcnt, boff, NB, E, rp, N);
  k_bscat<<<gE, 256, 0, stream>>>(ei, boff, bfill, tmp, E);
  k_bfin <<<NB, 256, 0, stream>>>(tmp, boff, ssrc, rp, dinv, N);

  int gemmG = (N + 127) / 128;
  int aggG  = (N + 3) / 4;
  const float* hin = x;
  for (int l = 0; l < 4; ++l){
    k_gemm<<<gemmG, 256, 0, stream>>>(hin, W[l], dinv, hw, N);
    k_agg <<<aggG, 256, 0, stream>>>(hw, rp, ssrc, dinv, B[l], h, N);
    hin = h;
  }
  k_pool1<<<G * PSPLIT, 256, 0, stream>>>(h, gst, pmx, psm);
  k_head <<<G, 128, 0, stream>>>(pmx, psm, gst, Wl, bl, out);
}